// Round 5
// baseline (422.486 us; speedup 1.0000x reference)
//
#include <hip/hip_runtime.h>

// Problem constants
#define BB  2
#define SS  2048
#define DD  2048
#define HH  16
#define HDD 128
#define BSR 4096   // BB*SS rows

using short8  = __attribute__((ext_vector_type(8))) short;
using floatx4 = __attribute__((ext_vector_type(4))) float;

__device__ __forceinline__ float bf2f(unsigned short u) {
  return __uint_as_float(((unsigned int)u) << 16);
}
__device__ __forceinline__ unsigned short f2bf(float f) {
  unsigned int u = __float_as_uint(f);
  u += 0x7fffu + ((u >> 16) & 1u);   // round-to-nearest-even
  return (unsigned short)(u >> 16);
}
// pack two floats -> two bf16 (rne) in one u32 (a=low, b=high)
__device__ __forceinline__ unsigned int pk2bf(float a, float b) {
  unsigned int ua = __float_as_uint(a);
  ua += 0x7fffu + ((ua >> 16) & 1u);
  unsigned int ub = __float_as_uint(b);
  ub += 0x7fffu + ((ub >> 16) & 1u);
  return (ua >> 16) | (ub & 0xffff0000u);
}
// fast 2^x (scores are kept in log2 domain)
__device__ __forceinline__ float fexp2(float x) {
#if __has_builtin(__builtin_amdgcn_exp2f)
  return __builtin_amdgcn_exp2f(x);
#else
  return __expf(x * 0.6931471805599453f);
#endif
}
// async global->LDS, 16 bytes per lane. LDS dest must be wave-uniform base + lane*16.
__device__ __forceinline__ void gl_lds16(const void* g, void* l) {
  __builtin_amdgcn_global_load_lds(
      (__attribute__((address_space(1))) void*)g,
      (__attribute__((address_space(3))) void*)l, 16, 0, 0);
}

// ---------------- weight transpose + bf16 convert: Out[f][d] = W[d][f] ----------------
__global__ __launch_bounds__(256) void transpose_w(
    const float* __restrict__ Wq, const float* __restrict__ Wk,
    const float* __restrict__ Wv, const float* __restrict__ Wo,
    unsigned short* __restrict__ wqkvt, unsigned short* __restrict__ wot)
{
  __shared__ float tile[32][33];
  const float* W; unsigned short* Out;
  int z = blockIdx.z;
  if      (z == 0) { W = Wq; Out = wqkvt; }
  else if (z == 1) { W = Wk; Out = wqkvt + (size_t)DD * DD; }
  else if (z == 2) { W = Wv; Out = wqkvt + 2 * (size_t)DD * DD; }
  else             { W = Wo; Out = wot; }
  int tx = threadIdx.x, ty = threadIdx.y;
  int d0 = blockIdx.y * 32, f0 = blockIdx.x * 32;
#pragma unroll
  for (int i = 0; i < 4; i++)
    tile[ty + i * 8][tx] = W[(size_t)(d0 + ty + i * 8) * DD + f0 + tx];
  __syncthreads();
#pragma unroll
  for (int i = 0; i < 4; i++)
    Out[(size_t)(f0 + ty + i * 8) * DD + d0 + tx] = f2bf(tile[tx][ty + i * 8]);
}

// ---------------- x -> bf16 ----------------
__global__ __launch_bounds__(256) void conv_x(const float* __restrict__ x,
                                              unsigned short* __restrict__ xb)
{
  size_t i = ((size_t)blockIdx.x * 256 + threadIdx.x) * 4;
  float4 v = *(const float4*)(x + i);
  ushort4 o;
  o.x = f2bf(v.x); o.y = f2bf(v.y); o.z = f2bf(v.z); o.w = f2bf(v.w);
  *(ushort4*)(xb + i) = o;
}

// ---------------- RoPE cos/sin table: rtab[s][c] = (cos, sin), s<2048, c<64 --------
__global__ __launch_bounds__(256) void rope_tab(float2* __restrict__ rtab) {
  int idx = blockIdx.x * 256 + threadIdx.x;   // 2048*64 entries
  int s = idx >> 6, c = idx & 63;
  float inv = powf(10000.f, -(float)c * (1.f / 64.f));
  float ang = (float)s * inv;
  float sn, cc;
  sincosf(ang, &sn, &cc);
  rtab[idx] = make_float2(cc, sn);
}

// ---------------- fused QKV GEMM: 256x256 tile, faithful 8-phase template port ----
// C[4096,6144] = xb * wqkvt^T. BM=BN=256, BK=64, 8 waves (2Mx4N), wave 128x64,
// 16 MFMA per phase. Double-buffered 128 KB LDS.
// Phase skeleton (m201 template + rule-#18 fence):
//   {ds_read frags | 2x global_load_lds} -> s_barrier -> lgkmcnt(0)+sched_barrier(0)
//   -> setprio(1) -> 16 MFMA -> setprio(0) [-> vmcnt(6) at P4/P8] -> s_barrier
// Uniform staging calendar, 2 loads/phase (region provably free at stage time):
//   P1: buf1.A-hi(t+1)[always]  P2: buf0.B-lo(t+2)  P3: buf0.B-hi  P4: buf0.A-lo
//   P5: buf0.A-hi               P6: buf1.B-lo(t+3)  P7: buf1.B-hi  P8: buf1.A-lo
// Ledger: vmcnt(6) at P4/P8; outstanding 14 -> 6; every retired load >= 3 phases
// in flight; tile complete exactly before its first read.
// Epilogue: two 128-row passes through LDS (stride 258), bias+RoPE (q/k) or
// kappa-permuted [hd][s] transpose (v). Block covers 2 heads of one plane.
#define MFMA_QUAD(MB, NB, FB) \
  _Pragma("unroll") for (int m_ = 0; m_ < 4; m_++) \
  _Pragma("unroll") for (int n_ = 0; n_ < 2; n_++) \
  _Pragma("unroll") for (int kk_ = 0; kk_ < 2; kk_++) \
    acc[(MB)+m_][(NB)+n_] = __builtin_amdgcn_mfma_f32_16x16x32_bf16( \
        fa[m_][kk_], FB[n_][kk_], acc[(MB)+m_][(NB)+n_], 0, 0, 0);

#define PHASE_HEAD() do {                                    \
    __builtin_amdgcn_s_barrier();                            \
    asm volatile("s_waitcnt lgkmcnt(0)" ::: "memory");       \
    __builtin_amdgcn_sched_barrier(0);                       \
    __builtin_amdgcn_s_setprio(1);                           \
  } while (0)
#define PHASE_TAIL() do {                                    \
    __builtin_amdgcn_s_setprio(0);                           \
    __builtin_amdgcn_s_barrier();                            \
  } while (0)
#define PHASE_TAIL_W(FULL) do {                              \
    __builtin_amdgcn_s_setprio(0);                           \
    if (FULL) asm volatile("s_waitcnt vmcnt(6)" ::: "memory"); \
    else      asm volatile("s_waitcnt vmcnt(0)" ::: "memory"); \
    __builtin_amdgcn_s_barrier();                            \
  } while (0)

__global__ __launch_bounds__(512) void gemm_qkv(
    const unsigned short* __restrict__ A, const unsigned short* __restrict__ Bt,
    const float* __restrict__ bq, const float* __restrict__ bk,
    const float* __restrict__ bv, const float2* __restrict__ rtab,
    unsigned short* __restrict__ q_r, unsigned short* __restrict__ k_r,
    unsigned short* __restrict__ v_t)
{
  __shared__ unsigned short smem[65536];   // 128 KB: buf0{A,B} buf1{A,B}
  unsigned short* const AsP[2] = { smem,         smem + 32768 };
  unsigned short* const BsP[2] = { smem + 16384, smem + 49152 };
  const int K = DD;
  int t = threadIdx.x;
  int lane = t & 63, qd = lane >> 4, l16 = lane & 15;
  int w = t >> 6, wr = w >> 2, wc = w & 3;

  // XCD-aware swizzle (bijective: 384 % 8 == 0): each XCD gets 2 M-rows x 24 N.
  int bid = blockIdx.y * gridDim.x + blockIdx.x;    // 0..383
  int wg  = (bid & 7) * 48 + (bid >> 3);
  int n0 = (wg % 24) * 256;
  int m0 = (wg / 24) * 256;

  floatx4 zero4 = {0.f, 0.f, 0.f, 0.f};
  floatx4 acc[8][4];
#pragma unroll
  for (int i = 0; i < 8; i++)
#pragma unroll
    for (int j = 0; j < 4; j++) acc[i][j] = zero4;

  // staging: thread t loads logical chunk (t&7)^(row&7), stores at position (t&7)
  int srow = t >> 3;                                // 0..63 within 64-row group
  int schunk = ((t & 7) ^ (srow & 7)) * 8;
  const unsigned short* Ag = A  + (size_t)(m0 + srow) * K + schunk;
  const unsigned short* Bg = Bt + (size_t)(n0 + srow) * K + schunk;

  auto stA = [&](int bf, int kt, int half) {   // 128 rows = 2 loads
#pragma unroll
    for (int q = 0; q < 2; q++) {
      int c = half * 2 + q;
      gl_lds16(Ag + (size_t)c * 64 * K + kt * 64, AsP[bf] + ((size_t)c * 512 + t) * 8);
    }
  };
  auto stB = [&](int bf, int kt, int half) {   // 128 rows = 2 loads
#pragma unroll
    for (int q = 0; q < 2; q++) {
      int c = half * 2 + q;
      gl_lds16(Bg + (size_t)c * 64 * K + kt * 64, BsP[bf] + ((size_t)c * 512 + t) * 8);
    }
  };
  auto ldA = [&](int bf, int mf, int kk) -> short8 {
    int row = wr * 128 + mf * 16 + l16;
    return *(const short8*)&AsP[bf][row * 64 + (((kk * 4 + qd) ^ (l16 & 7)) * 8)];
  };
  auto ldB = [&](int bf, int nf, int kk) -> short8 {
    int row = wc * 64 + nf * 16 + l16;
    return *(const short8*)&BsP[bf][row * 64 + (((kk * 4 + qd) ^ (l16 & 7)) * 8)];
  };

  // prologue: tile0 fully (8 loads) + tile1 B-lo,B-hi,A-lo (6); retire tile0.
  stB(0, 0, 0); stB(0, 0, 1); stA(0, 0, 0); stA(0, 0, 1);
  stB(1, 1, 0); stB(1, 1, 1); stA(1, 1, 0);
  asm volatile("s_waitcnt vmcnt(6)" ::: "memory");
  __builtin_amdgcn_s_barrier();

  short8 fa[4][2], fbl[2][2], fbh[2][2];

#pragma unroll 1
  for (int i = 0; i < 16; i++) {
    const bool full = (i < 15);
    const int t2 = 2 * i + 2, t3 = 2 * i + 3;

    // ======== K-tile 2i from buf0 ========
    // P1: read A-lo + B-lo; stage buf1.A-hi(2i+1) [always]
#pragma unroll
    for (int m = 0; m < 4; m++) { fa[m][0] = ldA(0, m, 0); fa[m][1] = ldA(0, m, 1); }
#pragma unroll
    for (int n = 0; n < 2; n++) { fbl[n][0] = ldB(0, n, 0); fbl[n][1] = ldB(0, n, 1); }
    stA(1, 2 * i + 1, 1);
    PHASE_HEAD();
    MFMA_QUAD(0, 0, fbl);
    PHASE_TAIL();
    // P2: read B-hi; stage buf0.B-lo(2i+2) — buf0.B-lo reads done in P1
#pragma unroll
    for (int n = 0; n < 2; n++) { fbh[n][0] = ldB(0, 2 + n, 0); fbh[n][1] = ldB(0, 2 + n, 1); }
    if (full) stB(0, t2, 0);
    PHASE_HEAD();
    MFMA_QUAD(0, 2, fbh);
    PHASE_TAIL();
    // P3: read A-hi; stage buf0.B-hi(2i+2) — buf0.B-hi reads done in P2
#pragma unroll
    for (int m = 0; m < 4; m++) { fa[m][0] = ldA(0, 4 + m, 0); fa[m][1] = ldA(0, 4 + m, 1); }
    if (full) stB(0, t2, 1);
    PHASE_HEAD();
    MFMA_QUAD(4, 0, fbl);
    PHASE_TAIL();
    // P4: stage buf0.A-lo(2i+2) — buf0.A-lo reads done in P1; vmcnt(6):
    // retires tile 2i+1's 4 stage-pairs (youngest = P1's, 3 phases old)
    if (full) stA(0, t2, 0);
    PHASE_HEAD();
    MFMA_QUAD(4, 2, fbh);
    PHASE_TAIL_W(full);

    // ======== K-tile 2i+1 from buf1 ========
    // P5: read A-lo + B-lo; stage buf0.A-hi(2i+2) — buf0.A-hi reads done in P3
#pragma unroll
    for (int m = 0; m < 4; m++) { fa[m][0] = ldA(1, m, 0); fa[m][1] = ldA(1, m, 1); }
#pragma unroll
    for (int n = 0; n < 2; n++) { fbl[n][0] = ldB(1, n, 0); fbl[n][1] = ldB(1, n, 1); }
    if (full) stA(0, t2, 1);
    PHASE_HEAD();
    MFMA_QUAD(0, 0, fbl);
    PHASE_TAIL();
    // P6: read B-hi; stage buf1.B-lo(2i+3) — buf1.B-lo reads done in P5
#pragma unroll
    for (int n = 0; n < 2; n++) { fbh[n][0] = ldB(1, 2 + n, 0); fbh[n][1] = ldB(1, 2 + n, 1); }
    if (full) stB(1, t3, 0);
    PHASE_HEAD();
    MFMA_QUAD(0, 2, fbh);
    PHASE_TAIL();
    // P7: read A-hi; stage buf1.B-hi(2i+3) — buf1.B-hi reads done in P6
#pragma unroll
    for (int m = 0; m < 4; m++) { fa[m][0] = ldA(1, 4 + m, 0); fa[m][1] = ldA(1, 4 + m, 1); }
    if (full) stB(1, t3, 1);
    PHASE_HEAD();
    MFMA_QUAD(4, 0, fbl);
    PHASE_TAIL();
    // P8: stage buf1.A-lo(2i+3) — buf1.A-lo reads done in P5; vmcnt(6):
    // retires tile 2i+2's 4 stage-pairs (youngest = P5's, 3 phases old)
    if (full) stA(1, t3, 0);
    PHASE_HEAD();
    MFMA_QUAD(4, 2, fbh);
    PHASE_TAIL_W(full);
  }

  // ---- epilogue: two 128-row passes through LDS (stride 258, 66 KB) ----
  __syncthreads();
  int plane = n0 >> 11;                 // 0=q, 1=k, 2=v
  int h0 = (n0 >> 7) & 15;              // first of the 2 heads in this tile
  const float* bias = plane == 0 ? bq : (plane == 1 ? bk : bv);
  int bI = m0 >> 11, sbase = m0 & (SS - 1);
  const int CT = 258;
  unsigned short* Ct = smem;

#pragma unroll 1
  for (int half = 0; half < 2; half++) {
    if (wr == half) {
#pragma unroll
      for (int mf = 0; mf < 8; mf++)
#pragma unroll
        for (int nf = 0; nf < 4; nf++) {
          int rl = mf * 16 + qd * 4;
          int cl = wc * 64 + nf * 16 + l16;
          float bsv = bias[h0 * 128 + cl];
#pragma unroll
          for (int r = 0; r < 4; r++)
            Ct[(rl + r) * CT + cl] = f2bf(acc[mf][nf][r] + bsv);
        }
    }
    __syncthreads();
    if (plane < 2) {
      unsigned short* dst0 = (plane == 0 ? q_r : k_r) + (size_t)(bI * HH + h0) * SS * HDD;
      const float fac = (plane == 0) ? 0.12751744f : 1.0f;   // 1/sqrt(128)*log2(e)
#pragma unroll
      for (int it = 0; it < 16; it++) {
        int idx = it * 512 + t;
        int rl = idx >> 6;               // local row 0..127
        int u = idx & 63; int hh = u >> 5; int c2 = (u & 31) * 2;
        int s = sbase + half * 128 + rl;
        float4 cs = *(const float4*)&rtab[(size_t)s * 64 + c2];
        int cb = hh * 128 + c2;
        float a0 = bf2f(Ct[rl * CT + cb]);
        float a1 = bf2f(Ct[rl * CT + cb + 1]);
        float b0 = bf2f(Ct[rl * CT + cb + 64]);
        float b1 = bf2f(Ct[rl * CT + cb + 65]);
        unsigned int lo = pk2bf((a0 * cs.x - b0 * cs.y) * fac,
                                (a1 * cs.z - b1 * cs.w) * fac);
        unsigned int hi = pk2bf((a0 * cs.y + b0 * cs.x) * fac,
                                (a1 * cs.w + b1 * cs.z) * fac);
        unsigned short* dst = dst0 + (size_t)hh * SS * HDD;
        size_t rowb = (size_t)s * HDD;
        *(unsigned int*)&dst[rowb + c2]      = lo;
        *(unsigned int*)&dst[rowb + c2 + 64] = hi;
      }
    } else {
      unsigned short* dst0 = v_t + (size_t)(bI * HH + h0) * HDD * SS;
#pragma unroll
      for (int it = 0; it < 32; it++) {
        int idx = it * 512 + t;
        int hdg = idx >> 6;              // global col 0..255 (2 heads)
        int sp = (idx & 63) * 2;         // local row, even
        unsigned short v0 = Ct[sp * CT + hdg];
        unsigned short v1 = Ct[(sp + 1) * CT + hdg];
        int hh = hdg >> 7, hd = hdg & 127;
        int y = sp & 63;
        int kap = ((y >> 5) & 1) * 32 + ((y >> 2) & 3) * 8 + ((y >> 4) & 1) * 4 + (y & 3);
        int sg = sbase + half * 128 + (sp & ~63) + kap;
        unsigned short* dst = dst0 + (size_t)hh * HDD * SS;
        *(unsigned int*)&dst[(size_t)hd * SS + sg] = ((unsigned int)v1 << 16) | v0;
      }
    }
    if (half == 0) __syncthreads();
  }
}

// ---------------- bf16 MFMA GEMM, B^T layout, BK=64 (final projection) -----------
template <bool OUTF32>
__global__ __launch_bounds__(256) void gemm_bt(
    const unsigned short* __restrict__ A, const unsigned short* __restrict__ Bt,
    const float* __restrict__ bias, void* __restrict__ Cout,
    int M, int N, int K)
{
  __shared__ unsigned short As[128 * 64];
  __shared__ unsigned short Bs[128 * 64];
  int t = threadIdx.x;
  int m0 = blockIdx.y * 128, n0 = blockIdx.x * 128;
  int w = t >> 6, lane = t & 63, qd = lane >> 4, l16 = lane & 15;
  int wm = (w >> 1) * 64, wn = (w & 1) * 64;
  floatx4 zero4 = {0.f, 0.f, 0.f, 0.f};
  floatx4 acc[4][4];
#pragma unroll
  for (int i = 0; i < 4; i++)
#pragma unroll
    for (int j = 0; j < 4; j++) acc[i][j] = zero4;

  int gchunk = (t & 7) ^ ((t >> 3) & 7);
  const unsigned short* Ab = A  + (size_t)(m0 + (t >> 3)) * K + gchunk * 8;
  const unsigned short* Bb = Bt + (size_t)(n0 + (t >> 3)) * K + gchunk * 8;
  size_t qK = (size_t)32 * K;

  for (int k0 = 0; k0 < K; k0 += 64) {
    __syncthreads();
#pragma unroll
    for (int c = 0; c < 4; c++) {
      gl_lds16(Ab + c * qK + k0, &As[(c * 256 + t) * 8]);
      gl_lds16(Bb + c * qK + k0, &Bs[(c * 256 + t) * 8]);
    }
    __syncthreads();
#pragma unroll
    for (int ks = 0; ks < 2; ks++) {
      int ch = ((ks * 4 + qd) ^ (l16 & 7)) * 8;
      short8 af[4], bfr[4];
#pragma unroll
      for (int i = 0; i < 4; i++)
        af[i] = *(const short8*)&As[(wm + i * 16 + l16) * 64 + ch];
#pragma unroll
      for (int j = 0; j < 4; j++)
        bfr[j] = *(const short8*)&Bs[(wn + j * 16 + l16) * 64 + ch];
#pragma unroll
      for (int i = 0; i < 4; i++)
#pragma unroll
        for (int j = 0; j < 4; j++)
          acc[i][j] = __builtin_amdgcn_mfma_f32_16x16x32_bf16(af[i], bfr[j], acc[i][j], 0, 0, 0);
    }
  }

#pragma unroll
  for (int i = 0; i < 4; i++)
#pragma unroll
    for (int j = 0; j < 4; j++) {
      int row = m0 + wm + i * 16 + qd * 4;
      int col = n0 + wn + j * 16 + l16;
      float bsv = bias ? bias[col] : 0.f;
#pragma unroll
      for (int r = 0; r < 4; r++) {
        float v = acc[i][j][r] + bsv;
        if (OUTF32) ((float*)Cout)[(size_t)(row + r) * N + col] = v;
        else ((unsigned short*)Cout)[(size_t)(row + r) * N + col] = f2bf(v);
      }
    }
}

// ---------------- flash attention v5: dbuf staging + XCD swizzle + exp2 ----------
__global__ __launch_bounds__(256, 2) void attn_kernel(
    const unsigned short* __restrict__ q_r, const unsigned short* __restrict__ k_r,
    const unsigned short* __restrict__ v_t, unsigned short* __restrict__ aout)
{
  __shared__ unsigned short Ks[2][64 * 128];   // [key][hd], swizzled chunks
  __shared__ unsigned short Vs[2][128 * 64];   // [hd][key-slot], swizzled chunks
  int t = threadIdx.x, w = t >> 6, lane = t & 63, qd = lane >> 4, l16 = lane & 15;
  int L = blockIdx.y * gridDim.x + blockIdx.x;
  int jj = L >> 3;
  int bh = (L & 7) * 4 + (jj >> 4);
  int q0 = (jj & 15) * 128;
  const unsigned short* qb = q_r + (size_t)bh * SS * HDD;
  const unsigned short* kb = k_r + (size_t)bh * SS * HDD;
  const unsigned short* vb = v_t + (size_t)bh * HDD * SS;

  short8 aq[2][4];
#pragma unroll
  for (int mi = 0; mi < 2; mi++)
#pragma unroll
    for (int ks = 0; ks < 4; ks++)
      aq[mi][ks] = *(const short8*)
          &qb[(size_t)(q0 + w * 32 + mi * 16 + l16) * HDD + ks * 32 + qd * 8];

  float m_i[2], l_i[2];
  floatx4 zero4 = {0.f, 0.f, 0.f, 0.f};
  floatx4 o[2][8];
#pragma unroll
  for (int mi = 0; mi < 2; mi++) { m_i[mi] = -1e30f; l_i[mi] = 0.f; }
#pragma unroll
  for (int mi = 0; mi < 2; mi++)
#pragma unroll
    for (int n = 0; n < 8; n++) o[mi][n] = zero4;

  auto stage = [&](int nb, int kt) {
#pragma unroll
    for (int c = 0; c < 4; c++) {
      int flat = c * 256 + t;
      int r = flat >> 4, cc = flat & 15;
      gl_lds16(kb + (size_t)(kt + r) * HDD + (cc ^ (r & 15)) * 8, &Ks[nb][flat * 8]);
    }
#pragma unroll
    for (int c = 0; c < 4; c++) {
      int flat = c * 256 + t;
      int r = flat >> 3, cc = flat & 7;
      gl_lds16(vb + (size_t)r * SS + kt + (cc ^ (r & 7)) * 8, &Vs[nb][flat * 8]);
    }
  };

  stage(0, 0);
  int buf = 0;

  for (int kt = 0; kt < SS; kt += 64) {
    __syncthreads();
    if (kt + 64 < SS) stage(buf ^ 1, kt + 64);

    floatx4 sc[2][4];
#pragma unroll
    for (int mi = 0; mi < 2; mi++)
#pragma unroll
      for (int j = 0; j < 4; j++) sc[mi][j] = zero4;
#pragma unroll
    for (int j = 0; j < 4; j++) {
      int krow = j * 16 + l16;
#pragma unroll
      for (int ks = 0; ks < 4; ks++) {
        int chunk = ks * 4 + qd;
        short8 kf = *(const short8*)&Ks[buf][krow * 128 + ((chunk ^ (krow & 15)) * 8)];
        sc[0][j] = __builtin_amdgcn_mfma_f32_16x16x32_bf16(kf, aq[0][ks], sc[0][j], 0, 0, 0);
        sc[1][j] = __builtin_amdgcn_mfma_f32_16x16x32_bf16(kf, aq[1][ks], sc[1][j], 0, 0, 0);
      }
    }

    float rmax[2];
#pragma unroll
    for (int mi = 0; mi < 2; mi++) {
      float m = sc[mi][0][0];
#pragma unroll
      for (int j = 0; j < 4; j++)
#pragma unroll
        for (int r = 0; r < 4; r++) m = fmaxf(m, sc[mi][j][r]);
      m = fmaxf(m, __shfl_xor(m, 16, 64));
      m = fmaxf(m, __shfl_xor(m, 32, 64));
      rmax[mi] = m;
    }

    bool up = (rmax[0] > m_i[0]) || (rmax[1] > m_i[1]);
    if (__ballot(up) != 0ull) {
#pragma unroll
      for (int mi = 0; mi < 2; mi++) {
        float mn = fmaxf(m_i[mi], rmax[mi]);
        float a = fexp2(m_i[mi] - mn);
        m_i[mi] = mn;
        l_i[mi] *= a;
#pragma unroll
        for (int n = 0; n < 8; n++)
#pragma unroll
          for (int r = 0; r < 4; r++) o[mi][n][r] *= a;
      }
    }

    unsigned int pr[2][4][2];
#pragma unroll
    for (int mi = 0; mi < 2; mi++) {
      float s0 = 0.f;
#pragma unroll
      for (int j = 0; j < 4; j++) {
        float p0 = fexp2(sc[mi][j][0] - m_i[mi]);
        float p1 = fexp2(sc[mi][j][1] - m_i[mi]);
        float p2 = fexp2(sc[mi][j][2] - m_i[mi]);
        float p3 = fexp2(sc[mi][j][3] - m_i[mi]);
        s0 += (p0 + p1) + (p2 + p3);
        pr[mi][j][0] = pk2bf(p0, p1);
        pr[mi][j][1] = pk2bf(p2, p3);
      }
      s0 += __shfl_xor(s0, 16, 64);
      s0 += __shfl_xor(s0, 32, 64);
      l_i[mi] += s0;
    }

#pragma unroll
    for (int n = 0; n < 8; n++) {
      int vrow = n * 16 + l16;
#pragma unroll
      for (int ks = 0; ks < 2; ks++) {
        int chunk = ks * 4 + qd;
        short8 av = *(const short8*)&Vs[buf][vrow * 64 + ((chunk ^ (vrow & 7)) * 8)];
        union { unsigned int u[4]; short8 v; } bp0, bp1;
        bp0.u[0] = pr[0][2 * ks][0];     bp0.u[1] = pr[0][2 * ks][1];
        bp0.u[2] = pr[0][2 * ks + 1][0]; bp0.u[3] = pr[0][2 * ks + 1][1];
        bp1.u[0] = pr[1][2 * ks][0];     bp1.u[1] = pr[1][2 * ks][1];
        bp1.u[2] = pr[1][2 * ks + 1][0]; bp1.u[3] = pr[1][2 * ks + 1][1];
        o[0][n] = __builtin_amdgcn_mfma_f32_16x16x32_bf16(av, bp0.v, o[0][n], 0, 0, 0);
        o[1][n] = __builtin_amdgcn_mfma_f32_16x16x32_bf16(av, bp1.v, o[1][n], 0, 0, 0);
      }
    }
    buf ^= 1;
  }

  int b = bh >> 4, h = bh & 15;
#pragma unroll
  for (int mi = 0; mi < 2; mi++) {
    int qrow = q0 + w * 32 + mi * 16 + l16;
    float inv_l = 1.f / l_i[mi];
    size_t base = ((size_t)(b * SS + qrow)) * DD + h * HDD;
#pragma unroll
    for (int n = 0; n < 8; n++) {
      uint2 pkd;
      pkd.x = pk2bf(o[mi][n][0] * inv_l, o[mi][n][1] * inv_l);
      pkd.y = pk2bf(o[mi][n][2] * inv_l, o[mi][n][3] * inv_l);
      *(uint2*)&aout[base + n * 16 + qd * 4] = pkd;
    }
  }
}

// ---------------- launch ----------------
extern "C" void kernel_launch(void* const* d_in, const int* in_sizes, int n_in,
                              void* d_out, int out_size, void* d_ws, size_t ws_size,
                              hipStream_t stream) {
  const float* x  = (const float*)d_in[0];
  const float* Wq = (const float*)d_in[1];
  const float* bq = (const float*)d_in[2];
  const float* Wk = (const float*)d_in[3];
  const float* bk = (const float*)d_in[4];
  const float* Wv = (const float*)d_in[5];
  const float* bv = (const float*)d_in[6];
  const float* Wo = (const float*)d_in[7];
  const float* bo = (const float*)d_in[8];
  float* out = (float*)d_out;

  char* ws = (char*)d_ws;
  unsigned short* xb      = (unsigned short*)(ws + 0);            // [BS,D] bf16, 16 MB
  unsigned short* wqkvt   = (unsigned short*)(ws + 16777216);     // [3D,D] bf16, 24 MB
  unsigned short* wot     = (unsigned short*)(ws + 41943040);     // [D,D]  bf16, 8 MB
  float2*         rtab    = (float2*)(ws + 50331648);             // [S,64] f32x2, 1 MB
  unsigned short* q_r     = (unsigned short*)(ws + 100663296);    // [B,H,S,HD] 16 MB
  unsigned short* k_r     = (unsigned short*)(ws + 117440512);    // [B,H,S,HD] 16 MB
  unsigned short* v_t     = (unsigned short*)(ws + 134217728);    // [B,H,HD,S] 16 MB
  unsigned short* attn_o  = xb;   // alias: xb dead after gemm_qkv

  transpose_w<<<dim3(DD / 32, DD / 32, 4), dim3(32, 8), 0, stream>>>(
      Wq, Wk, Wv, Wo, wqkvt, wot);
  conv_x<<<dim3((BSR * DD) / 1024), dim3(256), 0, stream>>>(x, xb);
  rope_tab<<<dim3((SS * 64) / 256), dim3(256), 0, stream>>>(rtab);
  gemm_qkv<<<dim3(3 * DD / 256, BSR / 256), dim3(512), 0, stream>>>(
      xb, wqkvt, bq, bk, bv, rtab, q_r, k_r, v_t);
  attn_kernel<<<dim3(SS / 128, BB * HH), dim3(256), 0, stream>>>(
      q_r, k_r, v_t, attn_o);
  gemm_bt<true><<<dim3(DD / 128, BSR / 128), dim3(256), 0, stream>>>(
      attn_o, wot, bo, out, BSR, DD, DD);
}

// Round 6
// 392.301 us; speedup vs baseline: 1.0769x; 1.0769x over previous
//
#include <hip/hip_runtime.h>

// Problem constants
#define BB  2
#define SS  2048
#define DD  2048
#define HH  16
#define HDD 128
#define BSR 4096   // BB*SS rows

using short8  = __attribute__((ext_vector_type(8))) short;
using floatx4 = __attribute__((ext_vector_type(4))) float;

__device__ __forceinline__ float bf2f(unsigned short u) {
  return __uint_as_float(((unsigned int)u) << 16);
}
__device__ __forceinline__ unsigned short f2bf(float f) {
  unsigned int u = __float_as_uint(f);
  u += 0x7fffu + ((u >> 16) & 1u);   // round-to-nearest-even
  return (unsigned short)(u >> 16);
}
// pack two floats -> two bf16 (rne) in one u32 (a=low, b=high)
__device__ __forceinline__ unsigned int pk2bf(float a, float b) {
  unsigned int ua = __float_as_uint(a);
  ua += 0x7fffu + ((ua >> 16) & 1u);
  unsigned int ub = __float_as_uint(b);
  ub += 0x7fffu + ((ub >> 16) & 1u);
  return (ua >> 16) | (ub & 0xffff0000u);
}
// fast 2^x (scores are kept in log2 domain)
__device__ __forceinline__ float fexp2(float x) {
#if __has_builtin(__builtin_amdgcn_exp2f)
  return __builtin_amdgcn_exp2f(x);
#else
  return __expf(x * 0.6931471805599453f);
#endif
}
// async global->LDS, 16 bytes per lane. LDS dest must be wave-uniform base + lane*16.
__device__ __forceinline__ void gl_lds16(const void* g, void* l) {
  __builtin_amdgcn_global_load_lds(
      (__attribute__((address_space(1))) void*)g,
      (__attribute__((address_space(3))) void*)l, 16, 0, 0);
}

// ---------------- fused prep: weight transpose (16384 blk) + x->bf16 (8192 blk)
// ---------------- + RoPE table (512 blk), one dispatch ----------------
__global__ __launch_bounds__(256) void prep(
    const float* __restrict__ x,
    const float* __restrict__ Wq, const float* __restrict__ Wk,
    const float* __restrict__ Wv, const float* __restrict__ Wo,
    unsigned short* __restrict__ xb,
    unsigned short* __restrict__ wqkvt, unsigned short* __restrict__ wot,
    float2* __restrict__ rtab)
{
  __shared__ float tile[32][33];
  int bid = blockIdx.x;
  int t = threadIdx.x;
  if (bid < 16384) {
    // weight transpose + bf16 convert: Out[f][d] = W[d][f]
    int z = bid >> 12;
    int rem = bid & 4095;
    int by = rem >> 6, bx = rem & 63;
    const float* W; unsigned short* Out;
    if      (z == 0) { W = Wq; Out = wqkvt; }
    else if (z == 1) { W = Wk; Out = wqkvt + (size_t)DD * DD; }
    else if (z == 2) { W = Wv; Out = wqkvt + 2 * (size_t)DD * DD; }
    else             { W = Wo; Out = wot; }
    int tx = t & 31, ty = t >> 5;
    int d0 = by * 32, f0 = bx * 32;
#pragma unroll
    for (int i = 0; i < 4; i++)
      tile[ty + i * 8][tx] = W[(size_t)(d0 + ty + i * 8) * DD + f0 + tx];
    __syncthreads();
#pragma unroll
    for (int i = 0; i < 4; i++)
      Out[(size_t)(f0 + ty + i * 8) * DD + d0 + tx] = f2bf(tile[tx][ty + i * 8]);
  } else if (bid < 16384 + 8192) {
    // x -> bf16
    size_t i = ((size_t)(bid - 16384) * 256 + t) * 4;
    float4 v = *(const float4*)(x + i);
    ushort4 o;
    o.x = f2bf(v.x); o.y = f2bf(v.y); o.z = f2bf(v.z); o.w = f2bf(v.w);
    *(ushort4*)(xb + i) = o;
  } else {
    // RoPE cos/sin table: rtab[s][c] = (cos, sin), s<2048, c<64
    int idx = (bid - 24576) * 256 + t;
    int s = idx >> 6, c = idx & 63;
    float inv = powf(10000.f, -(float)c * (1.f / 64.f));
    float ang = (float)s * inv;
    float sn, cc;
    sincosf(ang, &sn, &cc);
    rtab[idx] = make_float2(cc, sn);
  }
}

// ---------------- fused QKV GEMM + bias + RoPE + V-transpose (proven 125 µs) ----
// C[4096,6144] = xb * wqkvt^T. 128x128 tile == exactly one (plane, head) column
// block. Epilogue round-trips the tile through LDS (stride 132 = +4 pad) and
// writes q_r/k_r (bias+RoPE, q prescaled by 1/sqrt(HD)*log2e) or v_t
// (bias + [hd][s] transpose with kappa key-permute) directly.
__global__ __launch_bounds__(256) void gemm_qkv(
    const unsigned short* __restrict__ A, const unsigned short* __restrict__ Bt,
    const float* __restrict__ bq, const float* __restrict__ bk,
    const float* __restrict__ bv, const float2* __restrict__ rtab,
    unsigned short* __restrict__ q_r, unsigned short* __restrict__ k_r,
    unsigned short* __restrict__ v_t)
{
  __shared__ unsigned short smem[16896];   // As(8192)|Bs(8192); reused as Ct[128][132]
  unsigned short* As = smem;
  unsigned short* Bs = smem + 8192;
  const int K = DD;
  int t = threadIdx.x;
  int m0 = blockIdx.y * 128, n0 = blockIdx.x * 128;
  int w = t >> 6, lane = t & 63, qd = lane >> 4, l16 = lane & 15;
  int wm = (w >> 1) * 64, wn = (w & 1) * 64;
  floatx4 zero4 = {0.f, 0.f, 0.f, 0.f};
  floatx4 acc[4][4];
#pragma unroll
  for (int i = 0; i < 4; i++)
#pragma unroll
    for (int j = 0; j < 4; j++) acc[i][j] = zero4;

  int gchunk = (t & 7) ^ ((t >> 3) & 7);
  const unsigned short* Ab = A  + (size_t)(m0 + (t >> 3)) * K + gchunk * 8;
  const unsigned short* Bb = Bt + (size_t)(n0 + (t >> 3)) * K + gchunk * 8;
  size_t qK = (size_t)32 * K;

  for (int k0 = 0; k0 < K; k0 += 64) {
    __syncthreads();
#pragma unroll
    for (int c = 0; c < 4; c++) {
      gl_lds16(Ab + c * qK + k0, &As[(c * 256 + t) * 8]);
      gl_lds16(Bb + c * qK + k0, &Bs[(c * 256 + t) * 8]);
    }
    __syncthreads();
#pragma unroll
    for (int ks = 0; ks < 2; ks++) {
      int ch = ((ks * 4 + qd) ^ (l16 & 7)) * 8;
      short8 af[4], bfr[4];
#pragma unroll
      for (int i = 0; i < 4; i++)
        af[i] = *(const short8*)&As[(wm + i * 16 + l16) * 64 + ch];
#pragma unroll
      for (int j = 0; j < 4; j++)
        bfr[j] = *(const short8*)&Bs[(wn + j * 16 + l16) * 64 + ch];
#pragma unroll
      for (int i = 0; i < 4; i++)
#pragma unroll
        for (int j = 0; j < 4; j++)
          acc[i][j] = __builtin_amdgcn_mfma_f32_16x16x32_bf16(af[i], bfr[j], acc[i][j], 0, 0, 0);
    }
  }

  // ---- epilogue ----
  int plane = n0 >> 11;            // 0=q, 1=k, 2=v
  int h = (n0 >> 7) & 15;
  const float* bias = plane == 0 ? bq : (plane == 1 ? bk : bv);
  __syncthreads();                 // all waves done reading As/Bs
#pragma unroll
  for (int i = 0; i < 4; i++)
#pragma unroll
    for (int j = 0; j < 4; j++) {
      int rl = wm + i * 16 + qd * 4;
      int cl = wn + j * 16 + l16;
      float bsv = bias[h * 128 + cl];
#pragma unroll
      for (int r = 0; r < 4; r++)
        smem[(rl + r) * 132 + cl] = f2bf(acc[i][j][r] + bsv);
    }
  __syncthreads();

  int b = m0 >> 11, sbase = m0 & (SS - 1);
  if (plane < 2) {
    unsigned short* dst = (plane == 0 ? q_r : k_r) + (size_t)(b * HH + h) * SS * HDD;
    // q prescale: 1/sqrt(128) * log2(e); k unscaled
    const float fac = (plane == 0) ? 0.12751744f : 1.0f;
#pragma unroll
    for (int it = 0; it < 16; it++) {
      int idx = it * 256 + t;
      int rl = idx >> 5, c2 = (idx & 31) * 2;
      int s = sbase + rl;
      float4 cs = *(const float4*)&rtab[(size_t)s * 64 + c2]; // cos0,sin0,cos1,sin1
      float a0 = bf2f(smem[rl * 132 + c2]);
      float a1 = bf2f(smem[rl * 132 + c2 + 1]);
      float b0 = bf2f(smem[rl * 132 + c2 + 64]);
      float b1 = bf2f(smem[rl * 132 + c2 + 65]);
      unsigned int lo = pk2bf((a0 * cs.x - b0 * cs.y) * fac,
                              (a1 * cs.z - b1 * cs.w) * fac);
      unsigned int hi = pk2bf((a0 * cs.y + b0 * cs.x) * fac,
                              (a1 * cs.w + b1 * cs.z) * fac);
      size_t rowb = (size_t)s * HDD;
      *(unsigned int*)&dst[rowb + c2]      = lo;
      *(unsigned int*)&dst[rowb + c2 + 64] = hi;
    }
  } else {
    // v: transpose to [hd][s] with kappa key-permute within each 64-block
    unsigned short* dst = v_t + (size_t)(b * HH + h) * HDD * SS;
#pragma unroll
    for (int it = 0; it < 32; it++) {
      int idx = it * 256 + t;
      int hd = idx >> 6, sp = (idx & 63) * 2;
      unsigned short v0 = smem[sp * 132 + hd];
      unsigned short v1 = smem[(sp + 1) * 132 + hd];
      int y = sp & 63;
      int kap = ((y >> 5) & 1) * 32 + ((y >> 2) & 3) * 8 + ((y >> 4) & 1) * 4 + (y & 3);
      int sg = sbase + (sp & ~63) + kap;
      *(unsigned int*)&dst[(size_t)hd * SS + sg] = ((unsigned int)v1 << 16) | v0;
    }
  }
}

// ---------------- bf16 MFMA GEMM, B^T layout, BK=64 (final projection) -----------
template <bool OUTF32>
__global__ __launch_bounds__(256) void gemm_bt(
    const unsigned short* __restrict__ A, const unsigned short* __restrict__ Bt,
    const float* __restrict__ bias, void* __restrict__ Cout,
    int M, int N, int K)
{
  __shared__ unsigned short As[128 * 64];
  __shared__ unsigned short Bs[128 * 64];
  int t = threadIdx.x;
  int m0 = blockIdx.y * 128, n0 = blockIdx.x * 128;
  int w = t >> 6, lane = t & 63, qd = lane >> 4, l16 = lane & 15;
  int wm = (w >> 1) * 64, wn = (w & 1) * 64;
  floatx4 zero4 = {0.f, 0.f, 0.f, 0.f};
  floatx4 acc[4][4];
#pragma unroll
  for (int i = 0; i < 4; i++)
#pragma unroll
    for (int j = 0; j < 4; j++) acc[i][j] = zero4;

  int gchunk = (t & 7) ^ ((t >> 3) & 7);
  const unsigned short* Ab = A  + (size_t)(m0 + (t >> 3)) * K + gchunk * 8;
  const unsigned short* Bb = Bt + (size_t)(n0 + (t >> 3)) * K + gchunk * 8;
  size_t qK = (size_t)32 * K;

  for (int k0 = 0; k0 < K; k0 += 64) {
    __syncthreads();
#pragma unroll
    for (int c = 0; c < 4; c++) {
      gl_lds16(Ab + c * qK + k0, &As[(c * 256 + t) * 8]);
      gl_lds16(Bb + c * qK + k0, &Bs[(c * 256 + t) * 8]);
    }
    __syncthreads();
#pragma unroll
    for (int ks = 0; ks < 2; ks++) {
      int ch = ((ks * 4 + qd) ^ (l16 & 7)) * 8;
      short8 af[4], bfr[4];
#pragma unroll
      for (int i = 0; i < 4; i++)
        af[i] = *(const short8*)&As[(wm + i * 16 + l16) * 64 + ch];
#pragma unroll
      for (int j = 0; j < 4; j++)
        bfr[j] = *(const short8*)&Bs[(wn + j * 16 + l16) * 64 + ch];
#pragma unroll
      for (int i = 0; i < 4; i++)
#pragma unroll
        for (int j = 0; j < 4; j++)
          acc[i][j] = __builtin_amdgcn_mfma_f32_16x16x32_bf16(af[i], bfr[j], acc[i][j], 0, 0, 0);
    }
  }

#pragma unroll
  for (int i = 0; i < 4; i++)
#pragma unroll
    for (int j = 0; j < 4; j++) {
      int row = m0 + wm + i * 16 + qd * 4;
      int col = n0 + wn + j * 16 + l16;
      float bsv = bias ? bias[col] : 0.f;
#pragma unroll
      for (int r = 0; r < 4; r++) {
        float v = acc[i][j][r] + bsv;
        if (OUTF32) ((float*)Cout)[(size_t)(row + r) * N + col] = v;
        else ((unsigned short*)Cout)[(size_t)(row + r) * N + col] = f2bf(v);
      }
    }
}

// ---------------- flash attention v5 + T5 setprio around MFMA clusters ----------
// Scores arrive in log2 domain (q pre-scaled by 1/sqrt(HD)*log2e), so softmax
// uses native v_exp_f32 (2^x) with no per-exp multiply.
__global__ __launch_bounds__(256, 2) void attn_kernel(
    const unsigned short* __restrict__ q_r, const unsigned short* __restrict__ k_r,
    const unsigned short* __restrict__ v_t, unsigned short* __restrict__ aout)
{
  __shared__ unsigned short Ks[2][64 * 128];   // [key][hd], swizzled chunks
  __shared__ unsigned short Vs[2][128 * 64];   // [hd][key-slot], swizzled chunks
  int t = threadIdx.x, w = t >> 6, lane = t & 63, qd = lane >> 4, l16 = lane & 15;
  // XCD-aware remap: all 16 q-tiles of one head land on one XCD
  int L = blockIdx.y * gridDim.x + blockIdx.x;
  int jj = L >> 3;
  int bh = (L & 7) * 4 + (jj >> 4);
  int q0 = (jj & 15) * 128;
  const unsigned short* qb = q_r + (size_t)bh * SS * HDD;
  const unsigned short* kb = k_r + (size_t)bh * SS * HDD;
  const unsigned short* vb = v_t + (size_t)bh * HDD * SS;

  short8 aq[2][4];
#pragma unroll
  for (int mi = 0; mi < 2; mi++)
#pragma unroll
    for (int ks = 0; ks < 4; ks++)
      aq[mi][ks] = *(const short8*)
          &qb[(size_t)(q0 + w * 32 + mi * 16 + l16) * HDD + ks * 32 + qd * 8];

  float m_i[2], l_i[2];
  floatx4 zero4 = {0.f, 0.f, 0.f, 0.f};
  floatx4 o[2][8];   // O^T: rows hd (8 blocks of 16), cols qrow (mi)
#pragma unroll
  for (int mi = 0; mi < 2; mi++) { m_i[mi] = -1e30f; l_i[mi] = 0.f; }
#pragma unroll
  for (int mi = 0; mi < 2; mi++)
#pragma unroll
    for (int n = 0; n < 8; n++) o[mi][n] = zero4;

  auto stage = [&](int nb, int kt) {
#pragma unroll
    for (int c = 0; c < 4; c++) {       // K tile: 64 rows x 128 elems
      int flat = c * 256 + t;
      int r = flat >> 4, cc = flat & 15;
      gl_lds16(kb + (size_t)(kt + r) * HDD + (cc ^ (r & 15)) * 8, &Ks[nb][flat * 8]);
    }
#pragma unroll
    for (int c = 0; c < 4; c++) {       // V^T tile: 128 rows x 64 slots
      int flat = c * 256 + t;
      int r = flat >> 3, cc = flat & 7;
      gl_lds16(vb + (size_t)r * SS + kt + (cc ^ (r & 7)) * 8, &Vs[nb][flat * 8]);
    }
  };

  stage(0, 0);
  int buf = 0;

  for (int kt = 0; kt < SS; kt += 64) {
    __syncthreads();                     // drains staging of `buf`
    if (kt + 64 < SS) stage(buf ^ 1, kt + 64);   // prefetch next tile

    floatx4 sc[2][4];
#pragma unroll
    for (int mi = 0; mi < 2; mi++)
#pragma unroll
      for (int j = 0; j < 4; j++) sc[mi][j] = zero4;
    __builtin_amdgcn_s_setprio(1);
#pragma unroll
    for (int j = 0; j < 4; j++) {
      int krow = j * 16 + l16;
#pragma unroll
      for (int ks = 0; ks < 4; ks++) {
        int chunk = ks * 4 + qd;
        short8 kf = *(const short8*)&Ks[buf][krow * 128 + ((chunk ^ (krow & 15)) * 8)];
        sc[0][j] = __builtin_amdgcn_mfma_f32_16x16x32_bf16(kf, aq[0][ks], sc[0][j], 0, 0, 0);
        sc[1][j] = __builtin_amdgcn_mfma_f32_16x16x32_bf16(kf, aq[1][ks], sc[1][j], 0, 0, 0);
      }
    }
    __builtin_amdgcn_s_setprio(0);

    float rmax[2];
#pragma unroll
    for (int mi = 0; mi < 2; mi++) {
      float m = sc[mi][0][0];
#pragma unroll
      for (int j = 0; j < 4; j++)
#pragma unroll
        for (int r = 0; r < 4; r++) m = fmaxf(m, sc[mi][j][r]);
      m = fmaxf(m, __shfl_xor(m, 16, 64));
      m = fmaxf(m, __shfl_xor(m, 32, 64));
      rmax[mi] = m;
    }

    bool up = (rmax[0] > m_i[0]) || (rmax[1] > m_i[1]);
    if (__ballot(up) != 0ull) {
#pragma unroll
      for (int mi = 0; mi < 2; mi++) {
        float mn = fmaxf(m_i[mi], rmax[mi]);
        float a = fexp2(m_i[mi] - mn);
        m_i[mi] = mn;
        l_i[mi] *= a;
#pragma unroll
        for (int n = 0; n < 8; n++)
#pragma unroll
          for (int r = 0; r < 4; r++) o[mi][n][r] *= a;
      }
    }

    unsigned int pr[2][4][2];
#pragma unroll
    for (int mi = 0; mi < 2; mi++) {
      float s0 = 0.f;
#pragma unroll
      for (int j = 0; j < 4; j++) {
        float p0 = fexp2(sc[mi][j][0] - m_i[mi]);
        float p1 = fexp2(sc[mi][j][1] - m_i[mi]);
        float p2 = fexp2(sc[mi][j][2] - m_i[mi]);
        float p3 = fexp2(sc[mi][j][3] - m_i[mi]);
        s0 += (p0 + p1) + (p2 + p3);
        pr[mi][j][0] = pk2bf(p0, p1);
        pr[mi][j][1] = pk2bf(p2, p3);
      }
      s0 += __shfl_xor(s0, 16, 64);
      s0 += __shfl_xor(s0, 32, 64);
      l_i[mi] += s0;
    }

    __builtin_amdgcn_s_setprio(1);
#pragma unroll
    for (int n = 0; n < 8; n++) {
      int vrow = n * 16 + l16;
#pragma unroll
      for (int ks = 0; ks < 2; ks++) {
        int chunk = ks * 4 + qd;
        short8 av = *(const short8*)&Vs[buf][vrow * 64 + ((chunk ^ (vrow & 7)) * 8)];
        union { unsigned int u[4]; short8 v; } bp0, bp1;
        bp0.u[0] = pr[0][2 * ks][0];     bp0.u[1] = pr[0][2 * ks][1];
        bp0.u[2] = pr[0][2 * ks + 1][0]; bp0.u[3] = pr[0][2 * ks + 1][1];
        bp1.u[0] = pr[1][2 * ks][0];     bp1.u[1] = pr[1][2 * ks][1];
        bp1.u[2] = pr[1][2 * ks + 1][0]; bp1.u[3] = pr[1][2 * ks + 1][1];
        o[0][n] = __builtin_amdgcn_mfma_f32_16x16x32_bf16(av, bp0.v, o[0][n], 0, 0, 0);
        o[1][n] = __builtin_amdgcn_mfma_f32_16x16x32_bf16(av, bp1.v, o[1][n], 0, 0, 0);
      }
    }
    __builtin_amdgcn_s_setprio(0);
    buf ^= 1;
  }

  int b = bh >> 4, h = bh & 15;
#pragma unroll
  for (int mi = 0; mi < 2; mi++) {
    int qrow = q0 + w * 32 + mi * 16 + l16;
    float inv_l = 1.f / l_i[mi];
    size_t base = ((size_t)(b * SS + qrow)) * DD + h * HDD;
#pragma unroll
    for (int n = 0; n < 8; n++) {
      uint2 pkd;
      pkd.x = pk2bf(o[mi][n][0] * inv_l, o[mi][n][1] * inv_l);
      pkd.y = pk2bf(o[mi][n][2] * inv_l, o[mi][n][3] * inv_l);
      *(uint2*)&aout[base + n * 16 + qd * 4] = pkd;
    }
  }
}

// ---------------- launch ----------------
extern "C" void kernel_launch(void* const* d_in, const int* in_sizes, int n_in,
                              void* d_out, int out_size, void* d_ws, size_t ws_size,
                              hipStream_t stream) {
  const float* x  = (const float*)d_in[0];
  const float* Wq = (const float*)d_in[1];
  const float* bq = (const float*)d_in[2];
  const float* Wk = (const float*)d_in[3];
  const float* bk = (const float*)d_in[4];
  const float* Wv = (const float*)d_in[5];
  const float* bv = (const float*)d_in[6];
  const float* Wo = (const float*)d_in[7];
  const float* bo = (const float*)d_in[8];
  float* out = (float*)d_out;

  char* ws = (char*)d_ws;
  unsigned short* xb      = (unsigned short*)(ws + 0);            // [BS,D] bf16, 16 MB
  unsigned short* wqkvt   = (unsigned short*)(ws + 16777216);     // [3D,D] bf16, 24 MB
  unsigned short* wot     = (unsigned short*)(ws + 41943040);     // [D,D]  bf16, 8 MB
  float2*         rtab    = (float2*)(ws + 50331648);             // [S,64] f32x2, 1 MB
  unsigned short* q_r     = (unsigned short*)(ws + 100663296);    // [B,H,S,HD] 16 MB
  unsigned short* k_r     = (unsigned short*)(ws + 117440512);    // [B,H,S,HD] 16 MB
  unsigned short* v_t     = (unsigned short*)(ws + 134217728);    // [B,H,HD,S] 16 MB
  unsigned short* attn_o  = xb;   // alias: xb dead after gemm_qkv

  prep<<<dim3(25088), dim3(256), 0, stream>>>(
      x, Wq, Wk, Wv, Wo, xb, wqkvt, wot, rtab);
  gemm_qkv<<<dim3(3 * DD / 128, BSR / 128), dim3(256), 0, stream>>>(
      xb, wqkvt, bq, bk, bv, rtab, q_r, k_r, v_t);
  attn_kernel<<<dim3(SS / 128, BB * HH), dim3(256), 0, stream>>>(
      q_r, k_r, v_t, attn_o);
  gemm_bt<true><<<dim3(DD / 128, BSR / 128), dim3(256), 0, stream>>>(
      attn_o, wot, bo, out, BSR, DD, DD);
}